// Round 1
// baseline (96.150 us; speedup 1.0000x reference)
//
#include <hip/hip_runtime.h>

// Problem constants (from reference): B=16, L=4096, D=1024, K=64
#define Bn 16
#define Ln 4096
#define Dn 1024
#define Kn 64
#define CH 32            // tokens per chunk
#define NC (Ln / CH)     // 128 chunks per (b)

static __device__ __forceinline__ void acc4(float4& a, const float4 v) {
    a.x += v.x; a.y += v.y; a.z += v.z; a.w += v.w;
}
static __device__ __forceinline__ void acc4w(float4& a, const float4 v, float w) {
    a.x += v.x * w; a.y += v.y * w; a.z += v.z * w; a.w += v.w * w;
}

// ---------------------------------------------------------------------------
// K0: canonicalize sent_spans to int32. JAX default config downcasts the
// reference's jnp.int64 to int32, but detect int64 layout defensively:
// under int64 (little-endian), the high word of every element is 0 (values
// in [0,4096)); under int32, odd words are span 'end' values (~never all 0).
// ---------------------------------------------------------------------------
__global__ __launch_bounds__(256) void decode_spans_kernel(
    const unsigned int* __restrict__ raw, int* __restrict__ dec, int n_elems) {
    __shared__ unsigned int sred[256];
    unsigned int acc = 0;
    for (int i = threadIdx.x; i < n_elems / 2; i += 256)
        acc |= raw[2 * i + 1];
    sred[threadIdx.x] = acc;
    __syncthreads();
    for (int off = 128; off > 0; off >>= 1) {
        if ((int)threadIdx.x < off) sred[threadIdx.x] |= sred[threadIdx.x + off];
        __syncthreads();
    }
    const bool is64 = (sred[0] == 0u);
    for (int i = threadIdx.x; i < n_elems; i += 256)
        dec[i] = is64 ? (int)raw[2 * i] : (int)raw[i];
}

// ---------------------------------------------------------------------------
// K1: per-chunk partial sums over tokens, plain and attention-weighted.
// grid = B*NC blocks, 256 threads; thread t owns columns 4t..4t+3 (float4).
// Streams token_hidden exactly once (256 MB), fully coalesced.
// ---------------------------------------------------------------------------
__global__ __launch_bounds__(256) void chunk_sums_kernel(
    const float* __restrict__ x, const int* __restrict__ am,
    float* __restrict__ Sp, float* __restrict__ Sa) {
    const int bc = blockIdx.x;
    const int b = bc / NC;
    const int c = bc % NC;
    const int d0 = threadIdx.x * 4;

    const float* xrow = x + ((size_t)(b * Ln + c * CH)) * Dn + d0;
    const int* amrow = am + b * Ln + c * CH;

    float4 ap = {0.f, 0.f, 0.f, 0.f};
    float4 aa = {0.f, 0.f, 0.f, 0.f};
#pragma unroll 4
    for (int l = 0; l < CH; ++l) {
        const float4 v = *(const float4*)(xrow + (size_t)l * Dn);
        const float w = (float)amrow[l];   // uniform per iteration
        acc4(ap, v);
        acc4w(aa, v, w);
    }
    const size_t o = (size_t)bc * Dn + d0;
    *(float4*)(Sp + o) = ap;
    *(float4*)(Sa + o) = aa;
}

// ---------------------------------------------------------------------------
// K2: per-span pooling. grid = B*K blocks, 256 threads.
// mask_sum via block reduce over am[s:e]; span sum = interior chunk sums
// (from Sp/Sa) + edge token rows; divide; write H + sent_mask.
// use_chunks==0 -> direct summation fallback (no workspace needed).
// ---------------------------------------------------------------------------
__global__ __launch_bounds__(256) void span_pool_kernel(
    const float* __restrict__ x, const int* __restrict__ am,
    const int* __restrict__ spans, const float* __restrict__ Sp,
    const float* __restrict__ Sa, float* __restrict__ H,
    float* __restrict__ sent_mask, int use_chunks) {
    const int bk = blockIdx.x;          // b*K + k
    const int b = bk / Kn;

    int s = spans[2 * bk];
    int e = spans[2 * bk + 1];
    if (s < 0) s = 0; if (s > Ln) s = Ln;
    if (e < 0) e = 0; if (e > Ln) e = Ln;
    const int len = (e > s) ? (e - s) : 0;
    if (e < s) e = s;

    // ---- mask_sum = sum(am[s:e]) ----
    __shared__ int red[256];
    const int* amb = am + (size_t)b * Ln;
    int msum = 0;
    for (int l = s + (int)threadIdx.x; l < e; l += 256) msum += amb[l];
    red[threadIdx.x] = msum;
    __syncthreads();
    for (int off = 128; off > 0; off >>= 1) {
        if ((int)threadIdx.x < off) red[threadIdx.x] += red[threadIdx.x + off];
        __syncthreads();
    }
    msum = red[0];

    const bool use_am = (msum > 0);
    const bool valid = (len > 0);

    // interior chunk range [ca, cb); edges [s,e1hi) and [e2lo,e)
    int e1hi, e2lo, e2hi, ca = 0, cb = 0;
    bool mid = false;
    if (use_chunks) {
        ca = (s + CH - 1) / CH;
        cb = e / CH;
        mid = (ca <= cb);
    }
    if (mid) { e1hi = ca * CH; e2lo = cb * CH; e2hi = e; }
    else     { e1hi = e;       e2lo = 0;       e2hi = 0; }

    const int d0 = threadIdx.x * 4;
    float4 acc = {0.f, 0.f, 0.f, 0.f};

    if (mid) {
        const float* S = use_am ? Sa : Sp;
        const float* Sb = S + (size_t)b * NC * Dn + d0;
        for (int c = ca; c < cb; ++c)
            acc4(acc, *(const float4*)(Sb + (size_t)c * Dn));
    }

    const float* xb = x + (size_t)b * Ln * Dn + d0;
    for (int l = s; l < e1hi; ++l) {
        if (use_am) {
            const float w = (float)amb[l];
            if (w != 0.f) acc4w(acc, *(const float4*)(xb + (size_t)l * Dn), w);
        } else {
            acc4(acc, *(const float4*)(xb + (size_t)l * Dn));
        }
    }
    for (int l = e2lo; l < e2hi; ++l) {
        if (use_am) {
            const float w = (float)amb[l];
            if (w != 0.f) acc4w(acc, *(const float4*)(xb + (size_t)l * Dn), w);
        } else {
            acc4(acc, *(const float4*)(xb + (size_t)l * Dn));
        }
    }

    const float denom = use_am ? (float)msum : (float)len;
    const float inv = valid ? (1.0f / denom) : 0.0f;
    float4 outv;
    outv.x = acc.x * inv; outv.y = acc.y * inv;
    outv.z = acc.z * inv; outv.w = acc.w * inv;

    *(float4*)(H + (size_t)bk * Dn + d0) = outv;
    if (threadIdx.x == 0) sent_mask[bk] = valid ? 1.0f : 0.0f;
}

extern "C" void kernel_launch(void* const* d_in, const int* in_sizes, int n_in,
                              void* d_out, int out_size, void* d_ws, size_t ws_size,
                              hipStream_t stream) {
    const float* x = (const float*)d_in[0];
    const int* am = (const int*)d_in[1];
    const unsigned int* spans_raw = (const unsigned int*)d_in[2];

    float* H = (float*)d_out;
    float* sent_mask = H + (size_t)Bn * Kn * Dn;

    const size_t n_span_elems = 2 * (size_t)Bn * Kn;            // 2048
    const size_t dec_bytes = n_span_elems * sizeof(int);        // 8 KB
    const size_t s_elems = (size_t)Bn * NC * Dn;                // 2M floats
    const size_t need = dec_bytes + 2 * s_elems * sizeof(float); // ~16.8 MB

    // span canonicalization (needs 8 KB ws)
    const int* spans;
    if (ws_size >= dec_bytes) {
        int* dec = (int*)d_ws;
        decode_spans_kernel<<<1, 256, 0, stream>>>(spans_raw, dec, (int)n_span_elems);
        spans = dec;
    } else {
        spans = (const int*)spans_raw;  // assume int32 layout
    }

    const bool chunks = (ws_size >= need);
    float* Sp = (float*)((char*)d_ws + dec_bytes);
    float* Sa = Sp + s_elems;

    if (chunks)
        chunk_sums_kernel<<<Bn * NC, 256, 0, stream>>>(x, am, Sp, Sa);

    span_pool_kernel<<<Bn * Kn, 256, 0, stream>>>(
        x, am, spans, Sp, Sa, H, sent_mask, chunks ? 1 : 0);
}

// Round 2
// 86.773 us; speedup vs baseline: 1.1081x; 1.1081x over previous
//
#include <hip/hip_runtime.h>

// Problem constants (from reference): B=16, L=4096, D=1024, K=64
#define Bn 16
#define Ln 4096
#define Dn 1024
#define Kn 64
#define CH 32            // tokens per chunk
#define NC (Ln / CH)     // 128 chunks per batch row
#define NP (NC + 1)      // prefix rows per batch (exclusive prefix, P[0]=0)

static __device__ __forceinline__ void acc4(float4& a, const float4 v) {
    a.x += v.x; a.y += v.y; a.z += v.z; a.w += v.w;
}
static __device__ __forceinline__ void acc4w(float4& a, const float4 v, float w) {
    a.x += v.x * w; a.y += v.y * w; a.z += v.z * w; a.w += v.w * w;
}

// ---------------------------------------------------------------------------
// K0: canonicalize sent_spans to int32. JAX default config downcasts the
// reference's jnp.int64 to int32; detect int64 layout defensively (high
// words all zero => int64).
// ---------------------------------------------------------------------------
__global__ __launch_bounds__(256) void decode_spans_kernel(
    const unsigned int* __restrict__ raw, int* __restrict__ dec, int n_elems) {
    __shared__ unsigned int sred[256];
    unsigned int acc = 0;
    for (int i = threadIdx.x; i < n_elems / 2; i += 256)
        acc |= raw[2 * i + 1];
    sred[threadIdx.x] = acc;
    __syncthreads();
    for (int off = 128; off > 0; off >>= 1) {
        if ((int)threadIdx.x < off) sred[threadIdx.x] |= sred[threadIdx.x + off];
        __syncthreads();
    }
    const bool is64 = (sred[0] == 0u);
    for (int i = threadIdx.x; i < n_elems; i += 256)
        dec[i] = is64 ? (int)raw[2 * i] : (int)raw[i];
}

// ---------------------------------------------------------------------------
// K1: per-chunk partial sums (plain + attention-weighted), written into
// prefix-array slot c+1. grid = B*NC blocks, 256 threads, float4/thread.
// Streams token_hidden exactly once (256 MB), fully coalesced.
// ---------------------------------------------------------------------------
__global__ __launch_bounds__(256) void chunk_sums_kernel(
    const float* __restrict__ x, const int* __restrict__ am,
    float* __restrict__ Pp, float* __restrict__ Pa) {
    const int bc = blockIdx.x;
    const int b = bc / NC;
    const int c = bc % NC;
    const int d0 = threadIdx.x * 4;

    const float* xrow = x + ((size_t)(b * Ln + c * CH)) * Dn + d0;
    const int* amrow = am + b * Ln + c * CH;

    float4 ap = {0.f, 0.f, 0.f, 0.f};
    float4 aa = {0.f, 0.f, 0.f, 0.f};
#pragma unroll 4
    for (int l = 0; l < CH; ++l) {
        const float4 v = *(const float4*)(xrow + (size_t)l * Dn);
        const float w = (float)amrow[l];
        acc4(ap, v);
        acc4w(aa, v, w);
    }
    const size_t o = ((size_t)b * NP + (c + 1)) * Dn + d0;
    *(float4*)(Pp + o) = ap;
    *(float4*)(Pa + o) = aa;
}

// ---------------------------------------------------------------------------
// K1.5: in-place exclusive prefix over chunks. One thread per (b, 4-col)
// float4 column: 4096 threads = 64 blocks x 64. P[0]=0; P[c] = sum chunks <c.
// ---------------------------------------------------------------------------
__global__ __launch_bounds__(64) void prefix_kernel(
    float* __restrict__ Pp, float* __restrict__ Pa) {
    const int t = blockIdx.x * 64 + threadIdx.x;    // 0 .. B*D/4-1
    const int b = t >> 8;                           // / (D/4)
    const int d0 = (t & 255) * 4;

    float* pp = Pp + (size_t)b * NP * Dn + d0;
    float* pa = Pa + (size_t)b * NP * Dn + d0;
    float4 rp = {0.f, 0.f, 0.f, 0.f};
    float4 ra = {0.f, 0.f, 0.f, 0.f};
    *(float4*)pp = rp;
    *(float4*)pa = ra;
    for (int c = 1; c <= NC; ++c) {
        const float4 vp = *(const float4*)(pp + (size_t)c * Dn);
        const float4 va = *(const float4*)(pa + (size_t)c * Dn);
        acc4(rp, vp);
        acc4(ra, va);
        *(float4*)(pp + (size_t)c * Dn) = rp;
        *(float4*)(pa + (size_t)c * Dn) = ra;
    }
}

// ---------------------------------------------------------------------------
// K2: per-span pooling. grid = B*K blocks, 256 threads.
// mask_sum via block reduce; interior sum = P[cb]-P[ca] (2 float4 loads);
// edge tokens read directly from x (L3-resident after K1's stream).
// ---------------------------------------------------------------------------
__global__ __launch_bounds__(256) void span_pool_kernel(
    const float* __restrict__ x, const int* __restrict__ am,
    const int* __restrict__ spans, const float* __restrict__ Pp,
    const float* __restrict__ Pa, float* __restrict__ H,
    float* __restrict__ sent_mask, int use_chunks) {
    const int bk = blockIdx.x;          // b*K + k
    const int b = bk / Kn;

    int s = spans[2 * bk];
    int e = spans[2 * bk + 1];
    if (s < 0) s = 0; if (s > Ln) s = Ln;
    if (e < 0) e = 0; if (e > Ln) e = Ln;
    const int len = (e > s) ? (e - s) : 0;
    if (e < s) e = s;

    // ---- mask_sum = sum(am[s:e]) ----
    __shared__ int red[256];
    const int* amb = am + (size_t)b * Ln;
    int msum = 0;
    for (int l = s + (int)threadIdx.x; l < e; l += 256) msum += amb[l];
    red[threadIdx.x] = msum;
    __syncthreads();
    for (int off = 128; off > 0; off >>= 1) {
        if ((int)threadIdx.x < off) red[threadIdx.x] += red[threadIdx.x + off];
        __syncthreads();
    }
    msum = red[0];

    const bool use_am = (msum > 0);
    const bool valid = (len > 0);

    // interior chunk range [ca, cb); edges [s,e1hi) and [e2lo,e)
    int e1hi, e2lo, e2hi, ca = 0, cb = 0;
    bool mid = false;
    if (use_chunks) {
        ca = (s + CH - 1) / CH;
        cb = e / CH;
        mid = (ca <= cb);        // ca==cb => zero interior, still exact
    }
    if (mid) { e1hi = ca * CH; e2lo = cb * CH; e2hi = e; }
    else     { e1hi = e;       e2lo = 0;       e2hi = 0; }

    const int d0 = threadIdx.x * 4;
    float4 acc = {0.f, 0.f, 0.f, 0.f};

    if (mid) {
        const float* P = use_am ? Pa : Pp;
        const float* Pb = P + (size_t)b * NP * Dn + d0;
        const float4 hi = *(const float4*)(Pb + (size_t)cb * Dn);
        const float4 lo = *(const float4*)(Pb + (size_t)ca * Dn);
        acc.x = hi.x - lo.x; acc.y = hi.y - lo.y;
        acc.z = hi.z - lo.z; acc.w = hi.w - lo.w;
    }

    const float* xb = x + (size_t)b * Ln * Dn + d0;
    for (int l = s; l < e1hi; ++l) {
        if (use_am) {
            const float w = (float)amb[l];
            if (w != 0.f) acc4w(acc, *(const float4*)(xb + (size_t)l * Dn), w);
        } else {
            acc4(acc, *(const float4*)(xb + (size_t)l * Dn));
        }
    }
    for (int l = e2lo; l < e2hi; ++l) {
        if (use_am) {
            const float w = (float)amb[l];
            if (w != 0.f) acc4w(acc, *(const float4*)(xb + (size_t)l * Dn), w);
        } else {
            acc4(acc, *(const float4*)(xb + (size_t)l * Dn));
        }
    }

    const float denom = use_am ? (float)msum : (float)len;
    const float inv = valid ? (1.0f / denom) : 0.0f;
    float4 outv;
    outv.x = acc.x * inv; outv.y = acc.y * inv;
    outv.z = acc.z * inv; outv.w = acc.w * inv;

    *(float4*)(H + (size_t)bk * Dn + d0) = outv;
    if (threadIdx.x == 0) sent_mask[bk] = valid ? 1.0f : 0.0f;
}

extern "C" void kernel_launch(void* const* d_in, const int* in_sizes, int n_in,
                              void* d_out, int out_size, void* d_ws, size_t ws_size,
                              hipStream_t stream) {
    const float* x = (const float*)d_in[0];
    const int* am = (const int*)d_in[1];
    const unsigned int* spans_raw = (const unsigned int*)d_in[2];

    float* H = (float*)d_out;
    float* sent_mask = H + (size_t)Bn * Kn * Dn;

    const size_t n_span_elems = 2 * (size_t)Bn * Kn;             // 2048
    const size_t dec_bytes = n_span_elems * sizeof(int);         // 8 KB
    const size_t p_elems = (size_t)Bn * NP * Dn;                 // ~2.11M floats
    const size_t need = dec_bytes + 2 * p_elems * sizeof(float); // ~16.9 MB

    // span canonicalization (needs 8 KB ws)
    const int* spans;
    if (ws_size >= dec_bytes) {
        int* dec = (int*)d_ws;
        decode_spans_kernel<<<1, 256, 0, stream>>>(spans_raw, dec, (int)n_span_elems);
        spans = dec;
    } else {
        spans = (const int*)spans_raw;  // assume int32 layout
    }

    const bool chunks = (ws_size >= need);
    float* Pp = (float*)((char*)d_ws + dec_bytes);
    float* Pa = Pp + p_elems;

    if (chunks) {
        chunk_sums_kernel<<<Bn * NC, 256, 0, stream>>>(x, am, Pp, Pa);
        prefix_kernel<<<(Bn * Dn / 4) / 64, 64, 0, stream>>>(Pp, Pa);
    }

    span_pool_kernel<<<Bn * Kn, 256, 0, stream>>>(
        x, am, spans, Pp, Pa, H, sent_mask, chunks ? 1 : 0);
}

// Round 3
// 77.260 us; speedup vs baseline: 1.2445x; 1.1231x over previous
//
#include <hip/hip_runtime.h>

// Problem constants (from reference): B=16, L=4096, D=1024, K=64
#define Bn 16
#define Ln 4096
#define Dn 1024
#define Kn 64
#define CH 32            // tokens per chunk
#define NC (Ln / CH)     // 128 chunks per batch row
#define NP (NC + 1)      // prefix rows per batch (exclusive prefix, P[0]=0)
#define NSPAN (2 * Bn * Kn)   // 2048 span ints

static __device__ __forceinline__ void acc4(float4& a, const float4 v) {
    a.x += v.x; a.y += v.y; a.z += v.z; a.w += v.w;
}
static __device__ __forceinline__ void acc4w(float4& a, const float4 v, float w) {
    a.x += v.x * w; a.y += v.y * w; a.z += v.z * w; a.w += v.w * w;
}

// ---------------------------------------------------------------------------
// K1 (fused): grid = B*NC chunk blocks + B am-prefix blocks + 1 decode block.
//  - chunk blocks: per-chunk partial sums (plain + attention-weighted) into
//    prefix-array slot c+1. Streams token_hidden once (256 MB), coalesced.
//  - am-prefix blocks: exclusive token prefix of attention_mask per batch
//    (Pam[b][i] = sum am[b][0..i)), Pam[b][Ln] = total. 256-thread block scan.
//  - decode block: canonicalize sent_spans to int32 (detect int64 layout:
//    high words all zero => int64).
// ---------------------------------------------------------------------------
__global__ __launch_bounds__(256) void fused_stage1_kernel(
    const float* __restrict__ x, const int* __restrict__ am,
    const unsigned int* __restrict__ spans_raw,
    float* __restrict__ Pp, float* __restrict__ Pa,
    int* __restrict__ Pam, int* __restrict__ dec) {
    const int bc = blockIdx.x;

    if (bc < Bn * NC) {
        // ---- chunk sums ----
        const int b = bc / NC;
        const int c = bc % NC;
        const int d0 = threadIdx.x * 4;

        const float* xrow = x + ((size_t)(b * Ln + c * CH)) * Dn + d0;
        const int* amrow = am + b * Ln + c * CH;

        float4 ap = {0.f, 0.f, 0.f, 0.f};
        float4 aa = {0.f, 0.f, 0.f, 0.f};
#pragma unroll 4
        for (int l = 0; l < CH; ++l) {
            const float4 v = *(const float4*)(xrow + (size_t)l * Dn);
            const float w = (float)amrow[l];
            acc4(ap, v);
            acc4w(aa, v, w);
        }
        const size_t o = ((size_t)b * NP + (c + 1)) * Dn + d0;
        *(float4*)(Pp + o) = ap;
        *(float4*)(Pa + o) = aa;
    } else if (bc < Bn * NC + Bn) {
        // ---- am token-prefix for batch b ----
        const int b = bc - Bn * NC;
        const int t = threadIdx.x;
        const int i0 = t * 16;                      // 16 tokens per thread
        const int* amb = am + (size_t)b * Ln;
        int loc[16];
        int lsum = 0;
#pragma unroll
        for (int j = 0; j < 16; ++j) { loc[j] = amb[i0 + j]; lsum += loc[j]; }

        __shared__ int ssum[256];
        ssum[t] = lsum;
        __syncthreads();
        // Hillis-Steele inclusive scan over 256 thread sums
        for (int off = 1; off < 256; off <<= 1) {
            int v = (t >= off) ? ssum[t - off] : 0;
            __syncthreads();
            ssum[t] += v;
            __syncthreads();
        }
        int run = ssum[t] - lsum;                   // exclusive offset
        int* pam = Pam + (size_t)b * (Ln + 1);
#pragma unroll
        for (int j = 0; j < 16; ++j) { pam[i0 + j] = run; run += loc[j]; }
        if (t == 255) pam[Ln] = run;                // total
    } else {
        // ---- span decode ----
        __shared__ unsigned int sred[256];
        unsigned int acc = 0;
        for (int i = threadIdx.x; i < NSPAN / 2; i += 256)
            acc |= spans_raw[2 * i + 1];
        sred[threadIdx.x] = acc;
        __syncthreads();
        for (int off = 128; off > 0; off >>= 1) {
            if ((int)threadIdx.x < off) sred[threadIdx.x] |= sred[threadIdx.x + off];
            __syncthreads();
        }
        const bool is64 = (sred[0] == 0u);
        for (int i = threadIdx.x; i < NSPAN; i += 256)
            dec[i] = is64 ? (int)spans_raw[2 * i] : (int)spans_raw[i];
    }
}

// ---------------------------------------------------------------------------
// K1.5: in-place exclusive prefix over chunks. One thread per
// (array, b, scalar column): 2*16*1024 = 32768 threads = 128 blocks x 256.
// Coalesced scalar access; serial 128-step scan per thread.
// ---------------------------------------------------------------------------
__global__ __launch_bounds__(256) void prefix_kernel(
    float* __restrict__ Pp, float* __restrict__ Pa) {
    const int t = blockIdx.x * 256 + threadIdx.x;   // 0 .. 32767
    float* P = (t & 16384) ? Pa : Pp;
    const int rem = t & 16383;
    const int b = rem >> 10;
    const int col = rem & 1023;

    float* p = P + (size_t)b * NP * Dn + col;
    float r = 0.f;
    p[0] = 0.f;
#pragma unroll 8
    for (int c = 1; c <= NC; ++c) {
        r += p[(size_t)c * Dn];
        p[(size_t)c * Dn] = r;
    }
}

// ---------------------------------------------------------------------------
// K2: per-span pooling. grid = B*K blocks, 256 threads, no syncthreads.
// mask_sum = Pam[e]-Pam[s]; interior sum = P[cb]-P[ca]; edge tokens from x.
// ---------------------------------------------------------------------------
__global__ __launch_bounds__(256) void span_pool_kernel(
    const float* __restrict__ x, const int* __restrict__ am,
    const int* __restrict__ spans, const float* __restrict__ Pp,
    const float* __restrict__ Pa, const int* __restrict__ Pam,
    float* __restrict__ H, float* __restrict__ sent_mask) {
    const int bk = blockIdx.x;          // b*K + k
    const int b = bk / Kn;

    int s = spans[2 * bk];
    int e = spans[2 * bk + 1];
    if (s < 0) s = 0; if (s > Ln) s = Ln;
    if (e < 0) e = 0; if (e > Ln) e = Ln;
    const int len = (e > s) ? (e - s) : 0;
    if (e < s) e = s;

    const int* pam = Pam + (size_t)b * (Ln + 1);
    const int msum = pam[e] - pam[s];

    const bool use_am = (msum > 0);
    const bool valid = (len > 0);

    // interior chunk range [ca, cb); edges [s,e1hi) and [e2lo,e)
    const int ca = (s + CH - 1) / CH;
    const int cb = e / CH;
    const bool mid = (ca <= cb);
    int e1hi, e2lo, e2hi;
    if (mid) { e1hi = ca * CH; e2lo = cb * CH; e2hi = e; }
    else     { e1hi = e;       e2lo = 0;       e2hi = 0; }

    const int d0 = threadIdx.x * 4;
    float4 acc = {0.f, 0.f, 0.f, 0.f};

    if (mid && cb > ca) {
        const float* P = use_am ? Pa : Pp;
        const float* Pb = P + (size_t)b * NP * Dn + d0;
        const float4 hi = *(const float4*)(Pb + (size_t)cb * Dn);
        const float4 lo = *(const float4*)(Pb + (size_t)ca * Dn);
        acc.x = hi.x - lo.x; acc.y = hi.y - lo.y;
        acc.z = hi.z - lo.z; acc.w = hi.w - lo.w;
    }

    const int* amb = am + (size_t)b * Ln;
    const float* xb = x + (size_t)b * Ln * Dn + d0;
    for (int l = s; l < e1hi; ++l) {
        if (use_am) {
            const float w = (float)amb[l];
            if (w != 0.f) acc4w(acc, *(const float4*)(xb + (size_t)l * Dn), w);
        } else {
            acc4(acc, *(const float4*)(xb + (size_t)l * Dn));
        }
    }
    for (int l = e2lo; l < e2hi; ++l) {
        if (use_am) {
            const float w = (float)amb[l];
            if (w != 0.f) acc4w(acc, *(const float4*)(xb + (size_t)l * Dn), w);
        } else {
            acc4(acc, *(const float4*)(xb + (size_t)l * Dn));
        }
    }

    const float denom = use_am ? (float)msum : (float)len;
    const float inv = valid ? (1.0f / denom) : 0.0f;
    float4 outv;
    outv.x = acc.x * inv; outv.y = acc.y * inv;
    outv.z = acc.z * inv; outv.w = acc.w * inv;

    *(float4*)(H + (size_t)bk * Dn + d0) = outv;
    if (threadIdx.x == 0) sent_mask[bk] = valid ? 1.0f : 0.0f;
}

extern "C" void kernel_launch(void* const* d_in, const int* in_sizes, int n_in,
                              void* d_out, int out_size, void* d_ws, size_t ws_size,
                              hipStream_t stream) {
    const float* x = (const float*)d_in[0];
    const int* am = (const int*)d_in[1];
    const unsigned int* spans_raw = (const unsigned int*)d_in[2];

    float* H = (float*)d_out;
    float* sent_mask = H + (size_t)Bn * Kn * Dn;

    // workspace layout: dec | Pam | Pp | Pa
    const size_t dec_bytes = NSPAN * sizeof(int);                     // 8 KB
    const size_t pam_elems = (size_t)Bn * (Ln + 1);                   // 65552
    const size_t pam_bytes = pam_elems * sizeof(int);                 // 262 KB
    const size_t p_elems = (size_t)Bn * NP * Dn;                      // ~2.11M
    int* dec = (int*)d_ws;
    int* Pam = (int*)((char*)d_ws + dec_bytes);
    float* Pp = (float*)((char*)d_ws + dec_bytes + pam_bytes);
    float* Pa = Pp + p_elems;

    fused_stage1_kernel<<<Bn * NC + Bn + 1, 256, 0, stream>>>(
        x, am, spans_raw, Pp, Pa, Pam, dec);
    prefix_kernel<<<128, 256, 0, stream>>>(Pp, Pa);
    span_pool_kernel<<<Bn * Kn, 256, 0, stream>>>(
        x, am, dec, Pp, Pa, Pam, H, sent_mask);
}

// Round 4
// 65.274 us; speedup vs baseline: 1.4730x; 1.1836x over previous
//
#include <hip/hip_runtime.h>

// Problem constants (from reference): B=16, L=4096, D=1024, K=64
#define Bn 16
#define Ln 4096
#define Dn 1024
#define Kn 64
#define CH 16                 // tokens per fine chunk
#define NC (Ln / CH)          // 256 fine chunks per batch row
#define SEG 64                // fine chunks per segment
#define NSEG (NC / SEG)       // 4 segments per batch row
#define PFROWS (SEG + 1)      // 65 prefix slots per segment (slot 64 = total)
#define NSPAN (2 * Bn * Kn)   // 2048 span ints

static __device__ __forceinline__ void acc4(float4& a, const float4 v) {
    a.x += v.x; a.y += v.y; a.z += v.z; a.w += v.w;
}
static __device__ __forceinline__ void sub4(float4& a, const float4 v) {
    a.x -= v.x; a.y -= v.y; a.z -= v.z; a.w -= v.w;
}
static __device__ __forceinline__ void acc4w(float4& a, const float4 v, float w) {
    a.x += v.x * w; a.y += v.y * w; a.z += v.z * w; a.w += v.w * w;
}

// ---------------------------------------------------------------------------
// K1 (fused): grid = B*NC chunk blocks + B am-prefix blocks + 1 decode block.
//  - chunk blocks: attention-weighted per-chunk sums into segment-prefix
//    slot (seg, j+1). Streams token_hidden once (256 MB), coalesced.
//  - am-prefix blocks: exclusive token prefix of attention_mask per batch.
//  - decode block: canonicalize sent_spans to int32 (int64 layout detect).
// ---------------------------------------------------------------------------
__global__ __launch_bounds__(256) void fused_stage1_kernel(
    const float* __restrict__ x, const int* __restrict__ am,
    const unsigned int* __restrict__ spans_raw,
    float* __restrict__ Pf, int* __restrict__ Pam, int* __restrict__ dec) {
    const int bc = blockIdx.x;

    if (bc < Bn * NC) {
        // ---- weighted chunk sum ----
        const int b = bc / NC;
        const int c = bc % NC;
        const int d0 = threadIdx.x * 4;

        const float* xrow = x + ((size_t)(b * Ln + c * CH)) * Dn + d0;
        const int* amrow = am + b * Ln + c * CH;

        float4 aa = {0.f, 0.f, 0.f, 0.f};
#pragma unroll
        for (int l = 0; l < CH; ++l) {
            const float4 v = *(const float4*)(xrow + (size_t)l * Dn);
            const float w = (float)amrow[l];
            acc4w(aa, v, w);
        }
        const int seg = c >> 6;
        const int j = c & 63;
        const size_t o = ((size_t)(b * NSEG + seg) * PFROWS + (j + 1)) * Dn + d0;
        *(float4*)(Pf + o) = aa;
    } else if (bc < Bn * NC + Bn) {
        // ---- am token-prefix for batch b ----
        const int b = bc - Bn * NC;
        const int t = threadIdx.x;
        const int i0 = t * 16;
        const int* amb = am + (size_t)b * Ln;
        int loc[16];
        int lsum = 0;
#pragma unroll
        for (int j = 0; j < 16; ++j) { loc[j] = amb[i0 + j]; lsum += loc[j]; }

        __shared__ int ssum[256];
        ssum[t] = lsum;
        __syncthreads();
        for (int off = 1; off < 256; off <<= 1) {
            int v = (t >= off) ? ssum[t - off] : 0;
            __syncthreads();
            ssum[t] += v;
            __syncthreads();
        }
        int run = ssum[t] - lsum;                   // exclusive offset
        int* pam = Pam + (size_t)b * (Ln + 1);
#pragma unroll
        for (int j = 0; j < 16; ++j) { pam[i0 + j] = run; run += loc[j]; }
        if (t == 255) pam[Ln] = run;
    } else {
        // ---- span decode ----
        __shared__ unsigned int sred[256];
        unsigned int acc = 0;
        for (int i = threadIdx.x; i < NSPAN / 2; i += 256)
            acc |= spans_raw[2 * i + 1];
        sred[threadIdx.x] = acc;
        __syncthreads();
        for (int off = 128; off > 0; off >>= 1) {
            if ((int)threadIdx.x < off) sred[threadIdx.x] |= sred[threadIdx.x + off];
            __syncthreads();
        }
        const bool is64 = (sred[0] == 0u);
        for (int i = threadIdx.x; i < NSPAN; i += 256)
            dec[i] = is64 ? (int)spans_raw[2 * i] : (int)spans_raw[i];
    }
}

// ---------------------------------------------------------------------------
// K1.5: segmented in-place exclusive prefix. One thread per (b, seg, col):
// 16*4*1024 = 65536 threads = 256 blocks x 256 (4 waves/CU). 64 serial steps.
// Slot 0 = 0; slot j = sum of fine chunks < j within segment; slot 64 = total.
// ---------------------------------------------------------------------------
__global__ __launch_bounds__(256) void prefix_kernel(float* __restrict__ Pf) {
    const int t = blockIdx.x * 256 + threadIdx.x;   // 0 .. 65535
    const int col = t & 1023;
    const int seg = (t >> 10) & 3;
    const int b = t >> 12;

    float* p = Pf + (size_t)(b * NSEG + seg) * PFROWS * Dn + col;
    float r = 0.f;
    p[0] = 0.f;
#pragma unroll 8
    for (int j = 1; j <= SEG; ++j) {
        r += p[(size_t)j * Dn];
        p[(size_t)j * Dn] = r;
    }
}

// ---------------------------------------------------------------------------
// K2: per-span pooling. grid = B*K blocks, 256 threads, no syncthreads.
// mask_sum = Pam[e]-Pam[s]. use_am: interior from segmented prefixes
// (<=6 float4 loads) + weighted edge rows from x. !use_am (rare): direct
// plain-mean loop over [s,e).
// ---------------------------------------------------------------------------
__global__ __launch_bounds__(256) void span_pool_kernel(
    const float* __restrict__ x, const int* __restrict__ am,
    const int* __restrict__ spans, const float* __restrict__ Pf,
    const int* __restrict__ Pam, float* __restrict__ H,
    float* __restrict__ sent_mask) {
    const int bk = blockIdx.x;          // b*K + k
    const int b = bk / Kn;

    int s = spans[2 * bk];
    int e = spans[2 * bk + 1];
    if (s < 0) s = 0; if (s > Ln) s = Ln;
    if (e < 0) e = 0; if (e > Ln) e = Ln;
    const int len = (e > s) ? (e - s) : 0;
    if (e < s) e = s;

    const int* pam = Pam + (size_t)b * (Ln + 1);
    const int msum = pam[e] - pam[s];
    const bool use_am = (msum > 0);
    const bool valid = (len > 0);

    const int d0 = threadIdx.x * 4;
    const float* xb = x + (size_t)b * Ln * Dn + d0;
    const int* amb = am + (size_t)b * Ln;
    float4 acc = {0.f, 0.f, 0.f, 0.f};

    if (!use_am) {
        // rare: no attended tokens in span -> plain mean over [s,e)
        for (int l = s; l < e; ++l)
            acc4(acc, *(const float4*)(xb + (size_t)l * Dn));
    } else {
        // interior fine-chunk range [ca, cb); edges [s,e1hi) and [e2lo,e)
        const int ca = (s + CH - 1) / CH;
        const int cb = e / CH;
        int e1hi, e2lo, e2hi;
        if (ca <= cb) { e1hi = ca * CH; e2lo = cb * CH; e2hi = e; }
        else          { e1hi = e;       e2lo = 0;       e2hi = 0; }

        if (cb > ca) {
            const float* Pb = Pf + (size_t)b * NSEG * PFROWS * Dn + d0;
            const int sa = ca >> 6, ja = ca & 63;
            const int sb = cb >> 6, jb = cb & 63;
            if (sa == sb) {
                acc = *(const float4*)(Pb + (size_t)(sa * PFROWS + jb) * Dn);
                sub4(acc, *(const float4*)(Pb + (size_t)(sa * PFROWS + ja) * Dn));
            } else {
                acc = *(const float4*)(Pb + (size_t)(sa * PFROWS + SEG) * Dn);
                sub4(acc, *(const float4*)(Pb + (size_t)(sa * PFROWS + ja) * Dn));
                for (int ss = sa + 1; ss < sb; ++ss)
                    acc4(acc, *(const float4*)(Pb + (size_t)(ss * PFROWS + SEG) * Dn));
                if (jb > 0)
                    acc4(acc, *(const float4*)(Pb + (size_t)(sb * PFROWS + jb) * Dn));
            }
        }

        for (int l = s; l < e1hi; ++l) {
            const float w = (float)amb[l];
            if (w != 0.f) acc4w(acc, *(const float4*)(xb + (size_t)l * Dn), w);
        }
        for (int l = e2lo; l < e2hi; ++l) {
            const float w = (float)amb[l];
            if (w != 0.f) acc4w(acc, *(const float4*)(xb + (size_t)l * Dn), w);
        }
    }

    const float denom = use_am ? (float)msum : (float)len;
    const float inv = valid ? (1.0f / denom) : 0.0f;
    float4 outv;
    outv.x = acc.x * inv; outv.y = acc.y * inv;
    outv.z = acc.z * inv; outv.w = acc.w * inv;

    *(float4*)(H + (size_t)bk * Dn + d0) = outv;
    if (threadIdx.x == 0) sent_mask[bk] = valid ? 1.0f : 0.0f;
}

extern "C" void kernel_launch(void* const* d_in, const int* in_sizes, int n_in,
                              void* d_out, int out_size, void* d_ws, size_t ws_size,
                              hipStream_t stream) {
    const float* x = (const float*)d_in[0];
    const int* am = (const int*)d_in[1];
    const unsigned int* spans_raw = (const unsigned int*)d_in[2];

    float* H = (float*)d_out;
    float* sent_mask = H + (size_t)Bn * Kn * Dn;

    // workspace layout: dec | Pam | Pf
    const size_t dec_bytes = NSPAN * sizeof(int);                  // 8 KB
    const size_t pam_bytes = (size_t)Bn * (Ln + 1) * sizeof(int);  // 262 KB
    int* dec = (int*)d_ws;
    int* Pam = (int*)((char*)d_ws + dec_bytes);
    float* Pf = (float*)((char*)d_ws + dec_bytes + pam_bytes);     // ~17 MB

    fused_stage1_kernel<<<Bn * NC + Bn + 1, 256, 0, stream>>>(
        x, am, spans_raw, Pf, Pam, dec);
    prefix_kernel<<<256, 256, 0, stream>>>(Pf);
    span_pool_kernel<<<Bn * Kn, 256, 0, stream>>>(
        x, am, dec, Pf, Pam, H, sent_mask);
}